// Round 7
// baseline (324.830 us; speedup 1.0000x reference)
//
#include <hip/hip_runtime.h>

// MultiBoxLoss (SSD). B=128, P=8732, C=21, N=16 (runtime-derived).
// R7: all IoU divisions replaced by cross-multiplication compares
//     (argmax over quotients == argmax over cross-products, operands > 0);
//     k_final fused into k_hard via ticket-counter last-block finalize.
// k_pre  : block per (b,n) prior-argmax (cross-mult); zeroes npos/acc/ticket.
// k_fused: thread per (b,p): match label + CE + SL1 + conf_neg; atomic partials.
// k_hard : per-batch exact top-k (reg-resident 4-ary search on float bits);
//          last block combines acc -> out[0].
// ws: slot[B*P] f32 conf_neg, npos[B] i32, pfo[B*N] i32, acc[8] f32/i32.
// acc: [0]=loc f32, [1]=pos f32, [2]=hard f32, [3]=npos_total i32, [4]=ticket u32

#define MAXN 16
#define MAXE 16   // max ceil(P/1024) supported by k_hard

__device__ __forceinline__ float sl1f(float d) {
    float ad = fabsf(d);
    return ad < 1.0f ? 0.5f * d * d : ad - 0.5f;
}

// One BLOCK (256 thr) per (b,n): argmax over P priors of IoU(box[b,n], prior).
// Quotient compare done as cross-product: in/un > bi/bu  <=>  in*bu > bi*un
// (un,bu > 0). Init (bi,bu)=(-1,1) so the first candidate always wins.
// First-index ties: strict > over ascending p; reduce prefers better ratio,
// then smaller index (equal cross-products keep smaller index).
__global__ __launch_bounds__(256) void k_pre(
    const float* __restrict__ boxes,   // [B,N,4] xy
    const float* __restrict__ priors,  // [P,4] cxcy
    int P, int N,
    int* __restrict__ pfo,             // [B*N]
    int* __restrict__ npos,            // [B] zeroed here
    float* __restrict__ acc)           // [8] zeroed here
{
    __shared__ float rin[4], run[4];
    __shared__ int   rid[4];
    const int id = blockIdx.x;               // b*N + n
    const int tid = threadIdx.x;
    const int lane = tid & 63, wid = tid >> 6;

    if (tid == 0 && (id % N) == 0) npos[id / N] = 0;
    if (id == 0 && tid < 8) ((unsigned*)acc)[tid] = 0u;

    const float* bp = boxes + (size_t)id * 4;
    const float bx1 = bp[0], by1 = bp[1], bx2 = bp[2], by2 = bp[3];
    const float ba = (bx2 - bx1) * (by2 - by1);

    float bi = -1.0f, bu = 1.0f; int idx = 0x7fffffff;
#pragma unroll 2
    for (int p = tid; p < P; p += 256) {
        float4 pr = ((const float4*)priors)[p];
        float px1 = pr.x - pr.z * 0.5f, py1 = pr.y - pr.w * 0.5f;
        float px2 = pr.x + pr.z * 0.5f, py2 = pr.y + pr.w * 0.5f;
        float parea = (px2 - px1) * (py2 - py1);
        float iw = fmaxf(fminf(bx2, px2) - fmaxf(bx1, px1), 0.0f);
        float ih = fmaxf(fminf(by2, py2) - fmaxf(by1, py1), 0.0f);
        float in = iw * ih;
        float un = ba + parea - in;          // > 0 (areas positive)
        if (in * bu > bi * un) { bi = in; bu = un; idx = p; }  // first idx on tie
    }
#pragma unroll
    for (int off = 32; off > 0; off >>= 1) {
        float oin = __shfl_down(bi, off);
        float oun = __shfl_down(bu, off);
        int   oid = __shfl_down(idx, off);
        float a = oin * bu, c = bi * oun;
        if (a > c || (a == c && oid < idx)) { bi = oin; bu = oun; idx = oid; }
    }
    if (lane == 0) { rin[wid] = bi; run[wid] = bu; rid[wid] = idx; }
    __syncthreads();
    if (tid == 0) {
        for (int w = 1; w < 4; w++) {
            float oin = rin[w], oun = run[w]; int oid = rid[w];
            float a = oin * bu, c = bi * oun;
            if (a > c || (a == c && oid < idx)) { bi = oin; bu = oun; idx = oid; }
        }
        pfo[id] = idx;
    }
}

// Thread per (b,p), grid (nchunk, B). Per thread: best object (argmax axis=0,
// cross-mult, first-index ties), override (ascending scan, last match wins),
// label via bi < 0.5*bu; CE from LDS-staged scores; SmoothL1 on positives.
// Block partials go to global accumulators via atomics.
__global__ __launch_bounds__(256) void k_fused(
    const float* __restrict__ plocs,   // [B,P,4]
    const float* __restrict__ scores,  // [B*P, C]
    const float* __restrict__ boxes,   // [B,N,4]
    const int*   __restrict__ labels,  // [B,N]
    const float* __restrict__ priors,  // [P,4]
    const int*   __restrict__ pfo,     // [B*N]
    int P, int C, int N,
    float* __restrict__ conf_out,      // [B,P] conf_neg
    int*   __restrict__ npos,          // [B] (atomic)
    float* __restrict__ acc)           // [8]
{
    extern __shared__ float sh[];      // 256*C floats (score rows)
    __shared__ float sx1[MAXN], sy1[MAXN], sx2[MAXN], sy2[MAXN], barea[MAXN];
    __shared__ int   blab[MAXN], spfo[MAXN];
    __shared__ float redf[4], redp[4];
    __shared__ int   redi[4];

    const int b = blockIdx.y;
    const int tid = threadIdx.x;
    const int lane = tid & 63, wid = tid >> 6;
    if (N > MAXN) N = MAXN;
    const int p0 = blockIdx.x * 256;
    const int rows = min(256, P - p0);

    if (tid < N) {
        const float* bp = boxes + ((size_t)b * N + tid) * 4;
        float x1 = bp[0], y1 = bp[1], x2 = bp[2], y2 = bp[3];
        sx1[tid] = x1; sy1[tid] = y1; sx2[tid] = x2; sy2[tid] = y2;
        barea[tid] = (x2 - x1) * (y2 - y1);
        blab[tid] = labels[(size_t)b * N + tid];
        spfo[tid] = pfo[b * N + tid];
    }

    // Stage this block's score rows, coalesced float4 (256*C % 4 == 0).
    {
        const size_t f4base = ((size_t)b * P + p0) * C / 4;
        const int f4cnt = (rows * C + 3) / 4;
        const float4* __restrict__ s4 = (const float4*)scores;
        for (int j = tid; j < f4cnt; j += 256)
            ((float4*)sh)[j] = s4[f4base + j];
    }
    __syncthreads();

    const int p = p0 + tid;
    float locs = 0.0f, posc = 0.0f, conf = 0.0f;
    int np = 0;
    if (p < P) {
        float4 pr = ((const float4*)priors)[p];
        float px1 = pr.x - pr.z * 0.5f, py1 = pr.y - pr.w * 0.5f;
        float px2 = pr.x + pr.z * 0.5f, py2 = pr.y + pr.w * 0.5f;
        float parea = (px2 - px1) * (py2 - py1);
        float bi = -1.0f, bu = 1.0f; int bestn = 0;
#pragma unroll
        for (int n = 0; n < MAXN; n++) {
            if (n < N) {
                float iw = fmaxf(fminf(sx2[n], px2) - fmaxf(sx1[n], px1), 0.0f);
                float ih = fmaxf(fminf(sy2[n], py2) - fmaxf(sy1[n], py1), 0.0f);
                float in = iw * ih;
                float un = barea[n] + parea - in;
                if (in * bu > bi * un) { bi = in; bu = un; bestn = n; }
            }
        }
        // override: last n with pfo[n]==p wins (matches sequential scatter)
#pragma unroll
        for (int n = 0; n < MAXN; n++) {
            if (n < N && spfo[n] == p) { bestn = n; bi = 1.0f; bu = 1.0f; }
        }
        const int lab = (bi < 0.5f * bu) ? 0 : blab[bestn];  // iou < 0.5

        // CE from staged row
        const float* r = sh + tid * C;
        float m = -3.402823466e38f;
        for (int c = 0; c < C; c++) m = fmaxf(m, r[c]);
        float sum = 0.0f;
        for (int c = 0; c < C; c++) sum += __expf(r[c] - m);
        float ce = m + __logf(sum) - r[lab];   // -log_softmax[lab]

        if (lab != 0) {
            posc = ce; np = 1;                 // positive: pos sum
            int n = bestn;
            float cx = (sx1[n] + sx2[n]) * 0.5f, cy = (sy1[n] + sy2[n]) * 0.5f;
            float w = sx2[n] - sx1[n], h = sy2[n] - sy1[n];
            float g0 = (cx - pr.x) / (pr.z / 10.0f);
            float g1 = (cy - pr.y) / (pr.w / 10.0f);
            float g2 = logf(w / pr.z) * 5.0f;
            float g3 = logf(h / pr.w) * 5.0f;
            float4 pl = ((const float4*)plocs)[(size_t)b * P + p];
            locs = sl1f(pl.x - g0) + sl1f(pl.y - g1) + sl1f(pl.z - g2) + sl1f(pl.w - g3);
        } else {
            conf = ce;                         // negative: top-k candidate
        }
        conf_out[(size_t)b * P + p] = conf;
    }
#pragma unroll
    for (int off = 32; off > 0; off >>= 1) {
        locs += __shfl_down(locs, off);
        posc += __shfl_down(posc, off);
        np   += __shfl_down(np, off);
    }
    if (lane == 0) { redf[wid] = locs; redp[wid] = posc; redi[wid] = np; }
    __syncthreads();
    if (tid == 0) {
        float L = redf[0] + redf[1] + redf[2] + redf[3];
        float Pp = redp[0] + redp[1] + redp[2] + redp[3];
        int   c = redi[0] + redi[1] + redi[2] + redi[3];
        atomicAdd(&acc[0], L);
        atomicAdd(&acc[1], Pp);
        if (c) {
            atomicAdd(&npos[b], c);
            atomicAdd((int*)(acc + 3), c);
        }
    }
}

// Per-batch exact top-k sum; register-resident values; 4-ary search on float
// bit patterns (conf >= 0 so uint order == float order). Last-finishing block
// (device ticket) combines the accumulators and writes the scalar loss.
__global__ __launch_bounds__(1024, 4) void k_hard(
    const float* __restrict__ conf,  // [B,P] conf_neg (>=0; 0 at positives)
    const int* __restrict__ npos,
    int P,
    float* __restrict__ acc,         // [8]
    float* __restrict__ out)
{
    __shared__ int   redi[16 * 3];
    __shared__ float redf2[16];
    __shared__ int   redi2[16];
    const int b = blockIdx.x, tid = threadIdx.x;
    const int lane = tid & 63, wid = tid >> 6;
    const int nthr = blockDim.x, nw = nthr >> 6;
    const int ne = (P + nthr - 1) / nthr;        // 9 for P=8732
    long long kk = (long long)npos[b] * 3;
    int k = kk > P ? P : (int)kk;                // block-uniform

    float S = 0.0f;
    if (k > 0) {
        // Coalesced load into registers; sentinel 0 (never selected: search
        // thresholds >= 1, final pass uses strict > t with t >= 0).
        unsigned e[MAXE];
#pragma unroll
        for (int j = 0; j < MAXE; j++) {
            int p = j * nthr + tid;
            e[j] = (j < ne && p < P) ? __float_as_uint(conf[(size_t)b * P + p]) : 0u;
        }

        unsigned lo = 0u, hi = 0x7F800000u;
        while (lo < hi) {
            unsigned span = hi - lo;
            if (span >= 8) {
                unsigned q = span >> 2;
                unsigned m1 = lo + q, m2 = lo + 2 * q, m3 = lo + 3 * q;
                int c1 = 0, c2 = 0, c3 = 0;
#pragma unroll
                for (int j = 0; j < MAXE; j++) {
                    if (j < ne) {
                        unsigned v = e[j];
                        c1 += (int)__popcll(__ballot(v >= m1));
                        c2 += (int)__popcll(__ballot(v >= m2));
                        c3 += (int)__popcll(__ballot(v >= m3));
                    }
                }
                if (lane == 0) {
                    redi[wid * 3 + 0] = c1; redi[wid * 3 + 1] = c2; redi[wid * 3 + 2] = c3;
                }
                __syncthreads();
                int C1 = 0, C2 = 0, C3 = 0;
                for (int w = 0; w < nw; w++) {
                    C1 += redi[w * 3 + 0]; C2 += redi[w * 3 + 1]; C3 += redi[w * 3 + 2];
                }
                __syncthreads();
                if      (C3 >= k) lo = m3;
                else if (C2 >= k) { lo = m2; hi = m3 - 1; }
                else if (C1 >= k) { lo = m1; hi = m2 - 1; }
                else              hi = m1 - 1;
            } else {
                unsigned mid = lo + ((span + 1) >> 1);
                int c = 0;
#pragma unroll
                for (int j = 0; j < MAXE; j++)
                    if (j < ne) c += (int)__popcll(__ballot(e[j] >= mid));
                if (lane == 0) redi[wid * 3] = c;
                __syncthreads();
                int Cc = 0;
                for (int w = 0; w < nw; w++) Cc += redi[w * 3];
                __syncthreads();
                if (Cc >= k) lo = mid; else hi = mid - 1;
            }
        }

        float t = __uint_as_float(lo);
        float sgt = 0.0f; int cgt = 0;
#pragma unroll
        for (int j = 0; j < MAXE; j++) {
            if (j < ne) {
                float v = __uint_as_float(e[j]);
                if (v > t) { sgt += v; cgt++; }
            }
        }
#pragma unroll
        for (int off = 32; off > 0; off >>= 1) {
            sgt += __shfl_down(sgt, off);
            cgt += __shfl_down(cgt, off);
        }
        if (lane == 0) { redf2[wid] = sgt; redi2[wid] = cgt; }
        __syncthreads();
        if (tid == 0) {
            int Cg = 0;
            for (int w = 0; w < nw; w++) { S += redf2[w]; Cg += redi2[w]; }
            S += (float)(k - Cg) * t;   // ties at t handled exactly
        }
    }

    if (tid == 0) {
        atomicAdd(&acc[2], S);
        __threadfence();                         // order before ticket
        unsigned tk = atomicAdd((unsigned*)(acc + 4), 1u);
        if (tk == gridDim.x - 1) {               // all blocks' adds done
            float loc  = atomicAdd(&acc[0], 0.0f);   // device-coherent reads
            float pos  = atomicAdd(&acc[1], 0.0f);
            float hard = atomicAdd(&acc[2], 0.0f);
            int   Np   = atomicAdd((int*)(acc + 3), 0);
            float npf = (float)Np;
            out[0] = (hard + pos) / npf + loc / (npf * 4.0f);
        }
    }
}

extern "C" void kernel_launch(void* const* d_in, const int* in_sizes, int n_in,
                              void* d_out, int out_size, void* d_ws, size_t ws_size,
                              hipStream_t stream)
{
    const float* plocs  = (const float*)d_in[0];
    const float* scores = (const float*)d_in[1];
    const float* boxes  = (const float*)d_in[2];
    const int*   labels = (const int*)d_in[3];
    const float* priors = (const float*)d_in[4];

    int P = in_sizes[4] / 4;
    int B = in_sizes[0] / (P * 4);
    int C = in_sizes[1] / (in_sizes[0] / 4);
    int N = in_sizes[3] / B;
    int nchunk = (P + 255) / 256;
    int BN = B * N;

    char* w = (char*)d_ws;
    float* slot = (float*)w;  w += (size_t)B * P * sizeof(float);
    int*   npos = (int*)w;    w += (size_t)B * sizeof(int);
    int*   pfo  = (int*)w;    w += (size_t)BN * sizeof(int);
    w = (char*)(((uintptr_t)w + 63) & ~(uintptr_t)63);
    float* acc  = (float*)w;  // 8 words

    k_pre<<<BN, 256, 0, stream>>>(boxes, priors, P, N, pfo, npos, acc);

    dim3 ga(nchunk, B);
    size_t smf = (size_t)256 * C * sizeof(float);
    k_fused<<<ga, 256, smf, stream>>>(plocs, scores, boxes, labels, priors, pfo,
                                      P, C, N, slot, npos, acc);

    k_hard<<<B, 1024, 0, stream>>>(slot, npos, P, acc, (float*)d_out);
}

// Round 8
// 213.809 us; speedup vs baseline: 1.5193x; 1.5193x over previous
//
#include <hip/hip_runtime.h>

// MultiBoxLoss (SSD). B=128, P=8732, C=21, N=16 (runtime-derived).
// R8: R7's same-cache-line global atomics (4480 blocks x ~3 adds to acc[] =
//     ~12ns each serialized = +110us) reverted to per-block partial ARRAYS
//     (plain stores, deterministic). Kept: cross-mult IoU (div-free), 3
//     dispatches (k_final folded into k_hard via 128-block ticket finalize).
// k_pre  : block per (b,n) prior-argmax (cross-mult); zeroes npos + acc.
// k_fused: thread per (b,p): match label + CE (C=21 unrolled) + SL1 +
//          conf_neg; partials to locpart/pospart; npos[b] int atomic.
// k_hard : per-batch exact top-k (reg-resident 4-ary search on float bits);
//          one atomicAdd(acc_hard)/block + ticket; last block sums partials
//          (plain loads: written by the PREVIOUS kernel -> boundary-visible)
//          and writes out[0].
// ws: slot[B*P] f32 conf_neg, npos[B] i32, pfo[B*N] i32,
//     locpart[B*nchunk] f32, pospart[B*nchunk] f32, acc[2] (hard f32, ticket).

#define MAXN 16
#define MAXE 16   // max ceil(P/1024) supported by k_hard

__device__ __forceinline__ float sl1f(float d) {
    float ad = fabsf(d);
    return ad < 1.0f ? 0.5f * d * d : ad - 0.5f;
}

// One BLOCK (256 thr) per (b,n): argmax over P priors of IoU(box[b,n], prior).
// Quotient compare as cross-product: in/un > bi/bu <=> in*bu > bi*un (un,bu>0).
// First-index ties: strict > over ascending p; reduce prefers better ratio
// then smaller index.
__global__ __launch_bounds__(256) void k_pre(
    const float* __restrict__ boxes,   // [B,N,4] xy
    const float* __restrict__ priors,  // [P,4] cxcy
    int P, int N,
    int* __restrict__ pfo,             // [B*N]
    int* __restrict__ npos,            // [B] zeroed here
    float* __restrict__ acc)           // [2] zeroed here (hard, ticket)
{
    __shared__ float rin[4], run[4];
    __shared__ int   rid[4];
    const int id = blockIdx.x;               // b*N + n
    const int tid = threadIdx.x;
    const int lane = tid & 63, wid = tid >> 6;

    if (tid == 0 && (id % N) == 0) npos[id / N] = 0;
    if (id == 0 && tid < 2) ((unsigned*)acc)[tid] = 0u;

    const float* bp = boxes + (size_t)id * 4;
    const float bx1 = bp[0], by1 = bp[1], bx2 = bp[2], by2 = bp[3];
    const float ba = (bx2 - bx1) * (by2 - by1);

    float bi = -1.0f, bu = 1.0f; int idx = 0x7fffffff;
#pragma unroll 2
    for (int p = tid; p < P; p += 256) {
        float4 pr = ((const float4*)priors)[p];
        float px1 = pr.x - pr.z * 0.5f, py1 = pr.y - pr.w * 0.5f;
        float px2 = pr.x + pr.z * 0.5f, py2 = pr.y + pr.w * 0.5f;
        float parea = (px2 - px1) * (py2 - py1);
        float iw = fmaxf(fminf(bx2, px2) - fmaxf(bx1, px1), 0.0f);
        float ih = fmaxf(fminf(by2, py2) - fmaxf(by1, py1), 0.0f);
        float in = iw * ih;
        float un = ba + parea - in;          // > 0
        if (in * bu > bi * un) { bi = in; bu = un; idx = p; }  // first idx on tie
    }
#pragma unroll
    for (int off = 32; off > 0; off >>= 1) {
        float oin = __shfl_down(bi, off);
        float oun = __shfl_down(bu, off);
        int   oid = __shfl_down(idx, off);
        float a = oin * bu, c = bi * oun;
        if (a > c || (a == c && oid < idx)) { bi = oin; bu = oun; idx = oid; }
    }
    if (lane == 0) { rin[wid] = bi; run[wid] = bu; rid[wid] = idx; }
    __syncthreads();
    if (tid == 0) {
        for (int w = 1; w < 4; w++) {
            float oin = rin[w], oun = run[w]; int oid = rid[w];
            float a = oin * bu, c = bi * oun;
            if (a > c || (a == c && oid < idx)) { bi = oin; bu = oun; idx = oid; }
        }
        pfo[id] = idx;
    }
}

// Thread per (b,p), grid (nchunk, B). CT>0: compile-time class count.
template<int CT>
__global__ __launch_bounds__(256) void k_fused(
    const float* __restrict__ plocs,   // [B,P,4]
    const float* __restrict__ scores,  // [B*P, C]
    const float* __restrict__ boxes,   // [B,N,4]
    const int*   __restrict__ labels,  // [B,N]
    const float* __restrict__ priors,  // [P,4]
    const int*   __restrict__ pfo,     // [B*N]
    int P, int Crt, int N, int nchunk,
    float* __restrict__ conf_out,      // [B,P] conf_neg
    int*   __restrict__ npos,          // [B] (atomic, per-batch line)
    float* __restrict__ locpart,       // [B*nchunk]
    float* __restrict__ pospart)       // [B*nchunk]
{
    const int C = CT > 0 ? CT : Crt;
    extern __shared__ float sh[];      // 256*C floats (score rows)
    __shared__ float sx1[MAXN], sy1[MAXN], sx2[MAXN], sy2[MAXN], barea[MAXN];
    __shared__ int   blab[MAXN], spfo[MAXN];
    __shared__ float redf[4], redp[4];
    __shared__ int   redi[4];

    const int b = blockIdx.y;
    const int tid = threadIdx.x;
    const int lane = tid & 63, wid = tid >> 6;
    if (N > MAXN) N = MAXN;
    const int p0 = blockIdx.x * 256;
    const int rows = min(256, P - p0);

    if (tid < N) {
        const float* bp = boxes + ((size_t)b * N + tid) * 4;
        float x1 = bp[0], y1 = bp[1], x2 = bp[2], y2 = bp[3];
        sx1[tid] = x1; sy1[tid] = y1; sx2[tid] = x2; sy2[tid] = y2;
        barea[tid] = (x2 - x1) * (y2 - y1);
        blab[tid] = labels[(size_t)b * N + tid];
        spfo[tid] = pfo[b * N + tid];
    }

    // Stage this block's score rows, coalesced float4 (256*C % 4 == 0).
    {
        const size_t f4base = ((size_t)b * P + p0) * C / 4;
        const int f4cnt = (rows * C + 3) / 4;
        const float4* __restrict__ s4 = (const float4*)scores;
        for (int j = tid; j < f4cnt; j += 256)
            ((float4*)sh)[j] = s4[f4base + j];
    }
    __syncthreads();

    const int p = p0 + tid;
    float locs = 0.0f, posc = 0.0f, conf = 0.0f;
    int np = 0;
    if (p < P) {
        float4 pr = ((const float4*)priors)[p];
        float px1 = pr.x - pr.z * 0.5f, py1 = pr.y - pr.w * 0.5f;
        float px2 = pr.x + pr.z * 0.5f, py2 = pr.y + pr.w * 0.5f;
        float parea = (px2 - px1) * (py2 - py1);
        float bi = -1.0f, bu = 1.0f; int bestn = 0;
#pragma unroll
        for (int n = 0; n < MAXN; n++) {
            if (n < N) {
                float iw = fmaxf(fminf(sx2[n], px2) - fmaxf(sx1[n], px1), 0.0f);
                float ih = fmaxf(fminf(sy2[n], py2) - fmaxf(sy1[n], py1), 0.0f);
                float in = iw * ih;
                float un = barea[n] + parea - in;
                if (in * bu > bi * un) { bi = in; bu = un; bestn = n; }
            }
        }
        // override: last n with pfo[n]==p wins (matches sequential scatter)
#pragma unroll
        for (int n = 0; n < MAXN; n++) {
            if (n < N && spfo[n] == p) { bestn = n; bi = 1.0f; bu = 1.0f; }
        }
        const int lab = (bi < 0.5f * bu) ? 0 : blab[bestn];  // iou < 0.5

        // CE from staged row (serial order preserved; unrolled when CT>0)
        const float* r = sh + tid * C;
        float m = -3.402823466e38f;
#pragma unroll
        for (int c = 0; c < C; c++) m = fmaxf(m, r[c]);
        float sum = 0.0f;
#pragma unroll
        for (int c = 0; c < C; c++) sum += __expf(r[c] - m);
        float ce = m + __logf(sum) - r[lab];   // -log_softmax[lab]

        if (lab != 0) {
            posc = ce; np = 1;
            int n = bestn;
            float cx = (sx1[n] + sx2[n]) * 0.5f, cy = (sy1[n] + sy2[n]) * 0.5f;
            float w = sx2[n] - sx1[n], h = sy2[n] - sy1[n];
            float g0 = (cx - pr.x) / (pr.z / 10.0f);
            float g1 = (cy - pr.y) / (pr.w / 10.0f);
            float g2 = logf(w / pr.z) * 5.0f;
            float g3 = logf(h / pr.w) * 5.0f;
            float4 pl = ((const float4*)plocs)[(size_t)b * P + p];
            locs = sl1f(pl.x - g0) + sl1f(pl.y - g1) + sl1f(pl.z - g2) + sl1f(pl.w - g3);
        } else {
            conf = ce;
        }
        conf_out[(size_t)b * P + p] = conf;
    }
#pragma unroll
    for (int off = 32; off > 0; off >>= 1) {
        locs += __shfl_down(locs, off);
        posc += __shfl_down(posc, off);
        np   += __shfl_down(np, off);
    }
    if (lane == 0) { redf[wid] = locs; redp[wid] = posc; redi[wid] = np; }
    __syncthreads();
    if (tid == 0) {
        float L = redf[0] + redf[1] + redf[2] + redf[3];
        float Pp = redp[0] + redp[1] + redp[2] + redp[3];
        int   c = redi[0] + redi[1] + redi[2] + redi[3];
        if (c) atomicAdd(&npos[b], c);            // per-batch line: cheap
        locpart[b * nchunk + blockIdx.x] = L;     // plain stores: deterministic
        pospart[b * nchunk + blockIdx.x] = Pp;
    }
}

// Per-batch exact top-k sum; register-resident values; 4-ary search on float
// bit patterns (conf >= 0 so uint order == float order). One atomicAdd per
// block to acc[0] (128 total) + ticket in acc[1]; last block sums the
// k_fused partials (plain loads, kernel-boundary visible) and writes out[0].
__global__ __launch_bounds__(1024, 4) void k_hard(
    const float* __restrict__ conf,     // [B,P] conf_neg
    const int* __restrict__ npos,       // [B]
    const float* __restrict__ locpart,  // [nloc]
    const float* __restrict__ pospart,  // [nloc]
    int P, int B, int nloc,
    float* __restrict__ acc,            // [2]: hard sum, ticket
    float* __restrict__ out)
{
    __shared__ int   redi[16 * 3];
    __shared__ float redf2[16];
    __shared__ int   redi2[16];
    __shared__ float rl[16], rp[16];
    __shared__ int   rn[16], is_last;
    const int b = blockIdx.x, tid = threadIdx.x;
    const int lane = tid & 63, wid = tid >> 6;
    const int nthr = blockDim.x, nw = nthr >> 6;
    const int ne = (P + nthr - 1) / nthr;        // 9 for P=8732
    long long kk = (long long)npos[b] * 3;
    int k = kk > P ? P : (int)kk;                // block-uniform

    float S = 0.0f;
    if (k > 0) {
        // Coalesced load into registers; sentinel 0 (search thresholds >= 1,
        // final pass strict > t with t >= 0 -> never selected).
        unsigned e[MAXE];
#pragma unroll
        for (int j = 0; j < MAXE; j++) {
            int p = j * nthr + tid;
            e[j] = (j < ne && p < P) ? __float_as_uint(conf[(size_t)b * P + p]) : 0u;
        }

        // largest bit pattern t with count(x >= t) >= k == exact k-th largest
        unsigned lo = 0u, hi = 0x7F800000u;
        while (lo < hi) {
            unsigned span = hi - lo;
            if (span >= 8) {
                unsigned q = span >> 2;
                unsigned m1 = lo + q, m2 = lo + 2 * q, m3 = lo + 3 * q;
                int c1 = 0, c2 = 0, c3 = 0;
#pragma unroll
                for (int j = 0; j < MAXE; j++) {
                    if (j < ne) {
                        unsigned v = e[j];
                        c1 += (int)__popcll(__ballot(v >= m1));
                        c2 += (int)__popcll(__ballot(v >= m2));
                        c3 += (int)__popcll(__ballot(v >= m3));
                    }
                }
                if (lane == 0) {
                    redi[wid * 3 + 0] = c1; redi[wid * 3 + 1] = c2; redi[wid * 3 + 2] = c3;
                }
                __syncthreads();
                int C1 = 0, C2 = 0, C3 = 0;
                for (int w = 0; w < nw; w++) {
                    C1 += redi[w * 3 + 0]; C2 += redi[w * 3 + 1]; C3 += redi[w * 3 + 2];
                }
                __syncthreads();
                if      (C3 >= k) lo = m3;
                else if (C2 >= k) { lo = m2; hi = m3 - 1; }
                else if (C1 >= k) { lo = m1; hi = m2 - 1; }
                else              hi = m1 - 1;
            } else {
                unsigned mid = lo + ((span + 1) >> 1);
                int c = 0;
#pragma unroll
                for (int j = 0; j < MAXE; j++)
                    if (j < ne) c += (int)__popcll(__ballot(e[j] >= mid));
                if (lane == 0) redi[wid * 3] = c;
                __syncthreads();
                int Cc = 0;
                for (int w = 0; w < nw; w++) Cc += redi[w * 3];
                __syncthreads();
                if (Cc >= k) lo = mid; else hi = mid - 1;
            }
        }

        float t = __uint_as_float(lo);
        float sgt = 0.0f; int cgt = 0;
#pragma unroll
        for (int j = 0; j < MAXE; j++) {
            if (j < ne) {
                float v = __uint_as_float(e[j]);
                if (v > t) { sgt += v; cgt++; }
            }
        }
#pragma unroll
        for (int off = 32; off > 0; off >>= 1) {
            sgt += __shfl_down(sgt, off);
            cgt += __shfl_down(cgt, off);
        }
        if (lane == 0) { redf2[wid] = sgt; redi2[wid] = cgt; }
        __syncthreads();
        if (tid == 0) {
            int Cg = 0;
            for (int w = 0; w < nw; w++) { S += redf2[w]; Cg += redi2[w]; }
            S += (float)(k - Cg) * t;   // ties at t handled exactly
        }
        __syncthreads();
    }

    if (tid == 0) {
        atomicAdd(&acc[0], S);                   // 128 adds total: ~1.5us
        __threadfence();
        unsigned tk = atomicAdd((unsigned*)(acc + 1), 1u);
        is_last = (tk == (unsigned)gridDim.x - 1) ? 1 : 0;
    }
    __syncthreads();
    if (is_last) {
        float lp = 0.0f, pp = 0.0f; int np = 0;
        for (int i = tid; i < nloc; i += nthr) { lp += locpart[i]; pp += pospart[i]; }
        for (int i = tid; i < B; i += nthr) np += npos[i];
#pragma unroll
        for (int off = 32; off > 0; off >>= 1) {
            lp += __shfl_down(lp, off);
            pp += __shfl_down(pp, off);
            np += __shfl_down(np, off);
        }
        if (lane == 0) { rl[wid] = lp; rp[wid] = pp; rn[wid] = np; }
        __syncthreads();
        if (tid == 0) {
            float L = 0.0f, Pp = 0.0f; int Np = 0;
            for (int w = 0; w < nw; w++) { L += rl[w]; Pp += rp[w]; Np += rn[w]; }
            float hard = atomicAdd(&acc[0], 0.0f);   // device-coherent read
            float npf = (float)Np;
            out[0] = (hard + Pp) / npf + L / (npf * 4.0f);
        }
    }
}

extern "C" void kernel_launch(void* const* d_in, const int* in_sizes, int n_in,
                              void* d_out, int out_size, void* d_ws, size_t ws_size,
                              hipStream_t stream)
{
    const float* plocs  = (const float*)d_in[0];
    const float* scores = (const float*)d_in[1];
    const float* boxes  = (const float*)d_in[2];
    const int*   labels = (const int*)d_in[3];
    const float* priors = (const float*)d_in[4];

    int P = in_sizes[4] / 4;
    int B = in_sizes[0] / (P * 4);
    int C = in_sizes[1] / (in_sizes[0] / 4);
    int N = in_sizes[3] / B;
    int nchunk = (P + 255) / 256;
    int nloc = B * nchunk;
    int BN = B * N;

    char* w = (char*)d_ws;
    float* slot    = (float*)w;  w += (size_t)B * P * sizeof(float);
    int*   npos    = (int*)w;    w += (size_t)B * sizeof(int);
    int*   pfo     = (int*)w;    w += (size_t)BN * sizeof(int);
    float* locpart = (float*)w;  w += (size_t)nloc * sizeof(float);
    float* pospart = (float*)w;  w += (size_t)nloc * sizeof(float);
    w = (char*)(((uintptr_t)w + 63) & ~(uintptr_t)63);
    float* acc     = (float*)w;  // 2 words

    k_pre<<<BN, 256, 0, stream>>>(boxes, priors, P, N, pfo, npos, acc);

    dim3 ga(nchunk, B);
    size_t smf = (size_t)256 * C * sizeof(float);
    if (C == 21) {
        k_fused<21><<<ga, 256, smf, stream>>>(plocs, scores, boxes, labels, priors,
                                              pfo, P, C, N, nchunk, slot, npos,
                                              locpart, pospart);
    } else {
        k_fused<0><<<ga, 256, smf, stream>>>(plocs, scores, boxes, labels, priors,
                                             pfo, P, C, N, nchunk, slot, npos,
                                             locpart, pospart);
    }

    k_hard<<<B, 1024, 0, stream>>>(slot, npos, locpart, pospart,
                                   P, B, nloc, acc, (float*)d_out);
}